// Round 11
// baseline (80.317 us; speedup 1.0000x reference)
//
#include <hip/hip_runtime.h>
#include <hip/hip_bf16.h>
#include <cstdint>

#define DI __device__ __forceinline__

typedef __attribute__((ext_vector_type(8))) short short8;
typedef __attribute__((ext_vector_type(4))) float f32x4;

// ---------- bf16 helpers ----------
DI float bflo(uint32_t u) { return __builtin_bit_cast(float, (uint32_t)(u << 16)); }
DI float bfhi(uint32_t u) { return __builtin_bit_cast(float, (uint32_t)(u & 0xffff0000u)); }
// HW packed cvt (RNE); no builtin on gfx950
DI uint32_t cvtpk(float lo, float hi) {
    uint32_t r;
    asm("v_cvt_pk_bf16_f32 %0, %1, %2" : "=v"(r) : "v"(lo), "v"(hi));
    return r;
}
// async global->LDS, 16B/lane (dest = wave-uniform base + lane*16)
DI void gload16(const void* g, void* s) {
    __builtin_amdgcn_global_load_lds(
        (const __attribute__((address_space(1))) uint32_t*)g,
        (__attribute__((address_space(3))) uint32_t*)s, 16, 0, 0);
}
// m204 bijective XCD-chunk swizzle
DI int xcd_swizzle(int orig, int nwg) {
    const int q = nwg >> 3, r = nwg & 7;
    const int x = orig & 7, i = orig >> 3;
    return (x < r ? x * (q + 1) : r * (q + 1) + (x - r) * q) + i;
}

// ---------- problem constants ----------
constexpr int BATCH = 8, HH_IMG = 56, WW_IMG = 56, C = 192;
constexpr int HEADS = 6, HD = 32, NA = 486;
constexpr int NAP = 528;                               // 6 heads * 88 (padded)
constexpr int MROWS = BATCH * HH_IMG * WW_IMG;         // 25088
constexpr int KK = 192;
constexpr int TILE_B  = 49152;                         // B tile: 128 cols x 384B
constexpr int WTB_B   = 73728;                         // Wp frag-order

// =======================================================================
// prep_wts — r10's prep_all MINUS the x->xbf branch (bisect change).
// 93 blocks: WT unified tiles (18432 granules) + WTB (4608) + baP (528).
// =======================================================================
__global__ __launch_bounds__(256) void prep_wts(const float* __restrict__ Wv,
                                                const float* __restrict__ Wa,
                                                const float* __restrict__ Wp,
                                                const float* __restrict__ ba,
                                                uint8_t* __restrict__ WT,
                                                uint8_t* __restrict__ WTB,
                                                float* __restrict__ baP) {
    const int tid = blockIdx.x * 256 + threadIdx.x;
    if (tid < 18432) {
        const int s = tid % 24, rem = tid / 24;
        const int p = rem & 127, tile = rem >> 7;
        const int lc = (p >> 5) * 32 + 2 * (p & 15) + ((p >> 4) & 1);
        const int u  = tile * 128 + lc;               // unified col 0..767
        const float* src = nullptr; int nc = 0, col = 0;
        if (u < 192) { src = Wv; nc = 192; col = u; }
        else if (u < 720) {
            const int up = u - 192;
            const int head = up / 88, r88 = up - head * 88;
            if (r88 < 81) { src = Wa; nc = NA; col = head * 81 + r88; }
        }
        const int k0 = s * 8;
        uint32_t d[4];
#pragma unroll
        for (int e = 0; e < 4; ++e) {
            const float f0 = src ? src[(size_t)(k0 + 2 * e) * nc + col]     : 0.f;
            const float f1 = src ? src[(size_t)(k0 + 2 * e + 1) * nc + col] : 0.f;
            d[e] = cvtpk(f0, f1);
        }
        const int sb = (s * 16) ^ ((p & 7) << 4);
        *(uint4*)(WT + (size_t)tile * TILE_B + p * 384 + sb) =
            make_uint4(d[0], d[1], d[2], d[3]);
    } else if (tid < 18432 + 4608) {
        const int g = tid - 18432;
        const int l = g & 63, gg = g >> 6;
        const int ks = gg % 6, nrIdx = gg / 6;
        const int pp = nrIdx >> 1, h = nrIdx & 1;
        const int col = pp * 32 + 2 * (l & 15) + h;
        const int k0  = ks * 32 + (l >> 4) * 8;
        uint32_t d[4];
#pragma unroll
        for (int e = 0; e < 4; ++e) {
            const float f0 = Wp[(size_t)(k0 + 2 * e) * 192 + col];
            const float f1 = Wp[(size_t)(k0 + 2 * e + 1) * 192 + col];
            d[e] = cvtpk(f0, f1);
        }
        *(uint4*)(WTB + (size_t)g * 16) = make_uint4(d[0], d[1], d[2], d[3]);
    } else if (tid < 18432 + 4608 + NAP) {
        const int pc = tid - 18432 - 4608;
        const int head = pc / 88, r88 = pc - head * 88;
        baP[pc] = (r88 < 81) ? ba[head * 81 + r88] : 0.f;
    }
}

// =======================================================================
// gemm_fr — r10 version with ONE change (bisect): A-fragments built
// DIRECTLY from raw fp32 x (2x float4 + 4 cvt_pk per frag; lane l ->
// row (l&15), k-chunk (l>>4), identical mapping to the xbf path).
// B path unchanged: pre-swizzled WT tile via 12x global_load_lds.
// =======================================================================
__global__ __launch_bounds__(256, 2) void gemm_fr(
    const float* __restrict__ x,
    const uint8_t* __restrict__ WT,
    uint16_t* __restrict__ zOut, uint16_t* __restrict__ alogP,
    const float* __restrict__ baP) {
    __shared__ __align__(16) uint8_t sm[TILE_B];
    const int t    = threadIdx.x;
    const int wgid = xcd_swizzle(blockIdx.x, gridDim.x);
    const int mg   = wgid / 6, ti = wgid - mg * 6;
    const int m0   = mg * 128;
    const int l    = t & 63, wid = t >> 6;
    const int wr   = wid >> 1, wc = wid & 1;
    const int lr   = l & 15, lg = l >> 4;

    // ---- issue B DMA (async) ----
    const uint8_t* wt = WT + (size_t)ti * TILE_B;
#pragma unroll
    for (int i = 0; i < 12; ++i) {
        const int off = wid * 12288 + i * 1024;
        gload16(wt + off + l * 16, sm + off);
    }

    // ---- A fragments DIRECT from raw x (fp32 -> bf16 in regs) ----
    short8 aR[6][4];
#pragma unroll
    for (int ks = 0; ks < 6; ++ks)
#pragma unroll
        for (int mr = 0; mr < 4; ++mr) {
            const int row = (wr * 4 + mr) * 16 + lr;
            const float* xp = x + (size_t)(m0 + row) * KK + ks * 32 + lg * 8;
            const float4 v0 = *(const float4*)xp;
            const float4 v1 = *(const float4*)(xp + 4);
            uint4 o;
            o.x = cvtpk(v0.x, v0.y); o.y = cvtpk(v0.z, v0.w);
            o.z = cvtpk(v1.x, v1.y); o.w = cvtpk(v1.z, v1.w);
            aR[ks][mr] = __builtin_bit_cast(short8, o);
        }
    __syncthreads();       // drains B DMA once

    f32x4 acc[4][4];
#pragma unroll
    for (int mr = 0; mr < 4; ++mr)
#pragma unroll
        for (int nr = 0; nr < 4; ++nr) acc[mr][nr] = f32x4{0.f, 0.f, 0.f, 0.f};
#pragma unroll
    for (int ks = 0; ks < 6; ++ks) {
        const int cb = ks * 64 + lg * 16;
        short8 b[4];
#pragma unroll
        for (int nr = 0; nr < 4; ++nr) {
            const int rn = wc * 64 + nr * 16 + lr;
            b[nr] = *(const short8*)(sm + rn * 384 + (cb ^ ((rn & 7) << 4)));
        }
#pragma unroll
        for (int mr = 0; mr < 4; ++mr)
#pragma unroll
            for (int nr = 0; nr < 4; ++nr)
                acc[mr][nr] = __builtin_amdgcn_mfma_f32_16x16x32_bf16(
                    aR[ks][mr], b[nr], acc[mr][nr], 0, 0, 0);
    }

    const int gcol0 = ti * 128 + wc * 64;
#pragma unroll
    for (int pr = 0; pr < 2; ++pr) {
        const int uc = gcol0 + pr * 32 + 2 * lr;
        if (uc < 192) {
#pragma unroll
            for (int mr = 0; mr < 4; ++mr) {
                const size_t rb = (size_t)(m0 + wr * 64 + mr * 16 + lg * 4);
#pragma unroll
                for (int j = 0; j < 4; ++j)
                    *(uint32_t*)(zOut + (rb + j) * 192 + uc) =
                        cvtpk(acc[mr][2 * pr][j], acc[mr][2 * pr + 1][j]);
            }
        } else {
            const int pc = uc - 192;
            if (pc < NAP) {
                const float be = baP[pc], bo = baP[pc + 1];
#pragma unroll
                for (int mr = 0; mr < 4; ++mr) {
                    const size_t rb = (size_t)(m0 + wr * 64 + mr * 16 + lg * 4);
#pragma unroll
                    for (int j = 0; j < 4; ++j)
                        *(uint32_t*)(alogP + (rb + j) * NAP + pc) =
                            cvtpk(acc[mr][2 * pr][j] + be, acc[mr][2 * pr + 1][j] + bo);
                }
            }
        }
    }
}

// =======================================================================
// attn_fused — EXACT r10 version (verified passing; bank-conflict-free).
// =======================================================================
constexpr int TH = 4, TW = 8;
constexpr int HALO_W = TW + 4;                   // 12 (halo H = 8)
constexpr int HSTR = 80;                         // bytes per head (64+16 pad)
constexpr int PXSTR = HEADS * HSTR;              // 480 B per halo pixel
constexpr int VL_BYTES = 96 * PXSTR;             // 46080

__global__ __launch_bounds__(192) void attn_fused(const uint16_t* __restrict__ z,
                                                  const uint16_t* __restrict__ alogP,
                                                  const uint8_t* __restrict__ WTB,
                                                  const float* __restrict__ bp,
                                                  float* __restrict__ out) {
    __shared__ __align__(16) uint8_t smem[VL_BYTES];   // vl; yl aliases [0,12288)
    const int b   = blockIdx.z;
    const int ty0 = blockIdx.y * TH, tx0 = blockIdx.x * TW;
    const int t   = threadIdx.x;

    // ---- phase 1: stage z halo (head-padded layout) ----
#pragma unroll
    for (int it = 0; it < 12; ++it) {
        const int f  = t + it * 192;             // 96 px * 24 8-ch groups
        const int px = f / 24, c8 = f % 24;
        const int hy = px / HALO_W, hx = px % HALO_W;
        const int y = ty0 + hy - 2, x = tx0 + hx - 2;
        uint4 val = make_uint4(0u, 0u, 0u, 0u);
        if ((unsigned)y < HH_IMG && (unsigned)x < WW_IMG)
            val = *(const uint4*)&z[(((size_t)b * HH_IMG + y) * WW_IMG + x) * C + c8 * 8];
        *(uint4*)(smem + px * PXSTR + (c8 >> 2) * HSTR + (c8 & 3) * 16) = val;
    }

    const int n   = t % HEADS, pxl = t / HEADS;
    const int py  = pxl >> 3, px_ = pxl & 7;
    const int Py  = ty0 + py, Px = tx0 + px_;
    const float scl2 = 0.17677669529663687f * 1.4426950408889634f;  // scale*log2e

    // ---- phase 2: fold coefficients ----
    float cw[5][5] = {};
#pragma unroll
    for (int i = 0; i < 3; ++i)
#pragma unroll
        for (int j = 0; j < 3; ++j) {
            const int sy = Py - i + 1, sx = Px - j + 1;
            if ((unsigned)sy < HH_IMG && (unsigned)sx < WW_IMG) {
                const uint8_t* rp = (const uint8_t*)alogP +
                    (((size_t)b * HH_IMG + sy) * WW_IMG + sx) * (NAP * 2) + n * 176;
                const int win = i * 3 + j;
                const int off = win * 18, a0 = off & ~15, base = off - a0;
                const uint4 u0 = *(const uint4*)(rp + a0);
                const uint4 u1 = *(const uint4*)(rp + a0 + 16);
                const uint32_t dd[8] = {u0.x, u0.y, u0.z, u0.w, u1.x, u1.y, u1.z, u1.w};
                float w[9], s = 0.f;
#pragma unroll
                for (int q = 0; q < 9; ++q) {
                    const int bb = base + 2 * q;
                    const uint32_t dw = dd[bb >> 2];
                    const float f0 = (bb & 2) ? bfhi(dw) : bflo(dw);
                    w[q] = __builtin_amdgcn_exp2f(f0 * scl2);
                    s += w[q];
                }
                const float inv = __builtin_amdgcn_rcpf(s);
#pragma unroll
                for (int qi = 0; qi < 3; ++qi)
#pragma unroll
                    for (int qj = 0; qj < 3; ++qj)
                        cw[qi - i + 2][qj - j + 2] += w[qi * 3 + qj] * inv;
            }
        }
    __syncthreads();   // staging complete before gather

    // ---- phase 3: 25-offset gather (conflict-free banks) ----
    float acc[HD] = {};
#pragma unroll
    for (int dy = 0; dy < 5; ++dy)
#pragma unroll
        for (int dx = 0; dx < 5; ++dx) {
            const float wq = cw[dy][dx];
            const uint8_t* vp = smem + ((py + dy) * HALO_W + (px_ + dx)) * PXSTR + n * HSTR;
#pragma unroll
            for (int v8 = 0; v8 < 4; ++v8) {
                const uint4 raw = *(const uint4*)(vp + v8 * 16);
                const uint32_t r0 = raw.x, r1 = raw.y, r2 = raw.z, r3 = raw.w;
                acc[v8*8+0] = fmaf(wq, bflo(r0), acc[v8*8+0]);
                acc[v8*8+1] = fmaf(wq, bfhi(r0), acc[v8*8+1]);
                acc[v8*8+2] = fmaf(wq, bflo(r1), acc[v8*8+2]);
                acc[v8*8+3] = fmaf(wq, bfhi(r1), acc[v8*8+3]);
                acc[v8*8+4] = fmaf(wq, bflo(r2), acc[v8*8+4]);
                acc[v8*8+5] = fmaf(wq, bfhi(r2), acc[v8*8+5]);
                acc[v8*8+6] = fmaf(wq, bflo(r3), acc[v8*8+6]);
                acc[v8*8+7] = fmaf(wq, bfhi(r3), acc[v8*8+7]);
            }
        }
    __syncthreads();   // all gathers done -> vl region may be reused as yl

    // ---- ypre -> LDS (aliases vl; bf16, XOR-swizzled 384B rows) ----
    {
        uint8_t* pb = smem + pxl * 384;
        const int key = (pxl & 7) << 4;
#pragma unroll
        for (int g2 = 0; g2 < 4; ++g2) {
            uint4 o;
            o.x = cvtpk(acc[g2 * 8 + 0], acc[g2 * 8 + 1]);
            o.y = cvtpk(acc[g2 * 8 + 2], acc[g2 * 8 + 3]);
            o.z = cvtpk(acc[g2 * 8 + 4], acc[g2 * 8 + 5]);
            o.w = cvtpk(acc[g2 * 8 + 6], acc[g2 * 8 + 7]);
            *(uint4*)(pb + ((n * 64 + g2 * 16) ^ key)) = o;
        }
    }
    __syncthreads();

    // ---- phase 4: out = ypre @ Wp + bp ----
    const int l = t & 63, wid = t >> 6;
    const int lr = l & 15, lg = l >> 4;
    short8 aF[2][6];
#pragma unroll
    for (int r = 0; r < 2; ++r)
#pragma unroll
        for (int ks = 0; ks < 6; ++ks) {
            const int row = r * 16 + lr;
            aF[r][ks] = *(const short8*)(smem + row * 384 +
                          ((ks * 64 + lg * 16) ^ ((row & 7) << 4)));
        }
    f32x4 gacc[2][4];
#pragma unroll
    for (int r = 0; r < 2; ++r)
#pragma unroll
        for (int f = 0; f < 4; ++f) gacc[r][f] = f32x4{0.f, 0.f, 0.f, 0.f};
#pragma unroll
    for (int ks = 0; ks < 6; ++ks) {
        short8 bF[4];
#pragma unroll
        for (int f = 0; f < 4; ++f) {
            const int nrIdx = wid * 4 + f;
            bF[f] = *(const short8*)(WTB + (size_t)(((nrIdx * 6 + ks) * 64) + l) * 16);
        }
#pragma unroll
        for (int r = 0; r < 2; ++r)
#pragma unroll
            for (int f = 0; f < 4; ++f)
                gacc[r][f] = __builtin_amdgcn_mfma_f32_16x16x32_bf16(
                    aF[r][ks], bF[f], gacc[r][f], 0, 0, 0);
    }

#pragma unroll
    for (int pi = 0; pi < 2; ++pi) {
        const int col = wid * 64 + pi * 32 + 2 * lr;
        const float be = bp[col], bo = bp[col + 1];
#pragma unroll
        for (int r = 0; r < 2; ++r)
#pragma unroll
            for (int j = 0; j < 4; ++j) {
                const int prow = r * 16 + lg * 4 + j;
                const int gy = ty0 + (prow >> 3), gx = tx0 + (prow & 7);
                float* op = out + (((size_t)b * HH_IMG + gy) * WW_IMG + gx) * C + col;
                *(float2*)op = make_float2(gacc[r][2 * pi][j] + be,
                                           gacc[r][2 * pi + 1][j] + bo);
            }
    }
}

// =======================================================================
extern "C" void kernel_launch(void* const* d_in, const int* in_sizes, int n_in,
                              void* d_out, int out_size, void* d_ws, size_t ws_size,
                              hipStream_t stream) {
    const float* x  = (const float*)d_in[0];
    const float* Wv = (const float*)d_in[1];
    const float* Wa = (const float*)d_in[2];
    const float* ba = (const float*)d_in[3];
    const float* Wp = (const float*)d_in[4];
    const float* bp = (const float*)d_in[5];
    float* out = (float*)d_out;

    // ws: z | alogP | WT | WTB | baP  (xbf dropped)
    uint16_t* z     = (uint16_t*)d_ws;
    uint16_t* alogP = z + (size_t)MROWS * C;
    uint8_t*  WT    = (uint8_t*)(alogP + (size_t)MROWS * NAP);
    uint8_t*  WTB   = WT + 6 * (size_t)TILE_B;
    float*    baP   = (float*)(WTB + WTB_B);

    // prep: weight tiles + WTB + baP only (93 blocks)
    prep_wts<<<93, 256, 0, stream>>>(Wv, Wa, Wp, ba, WT, WTB, baP);
    // projections: A direct from raw x (bisect change), B from WT
    gemm_fr<<<(MROWS / 128) * 6, 256, 0, stream>>>(x, WT, z, alogP, baP);
    // softmax + fold + final GEMM -> out
    attn_fused<<<dim3(WW_IMG / TW, HH_IMG / TH, BATCH), dim3(192), 0, stream>>>(
        z, alogP, WTB, bp, out);
}

// Round 12
// 56.841 us; speedup vs baseline: 1.4130x; 1.4130x over previous
//
#include <hip/hip_runtime.h>
#include <hip/hip_bf16.h>
#include <cstdint>

#define DI __device__ __forceinline__

typedef __attribute__((ext_vector_type(8))) short short8;
typedef __attribute__((ext_vector_type(4))) float f32x4;

// ---------- bf16 helpers ----------
DI float bflo(uint32_t u) { return __builtin_bit_cast(float, (uint32_t)(u << 16)); }
DI float bfhi(uint32_t u) { return __builtin_bit_cast(float, (uint32_t)(u & 0xffff0000u)); }
DI uint32_t cvtpk(float lo, float hi) {
    uint32_t r;
    asm("v_cvt_pk_bf16_f32 %0, %1, %2" : "=v"(r) : "v"(lo), "v"(hi));
    return r;
}
// ---------- fp8 e4m3 helpers ----------
#if __has_builtin(__builtin_amdgcn_cvt_pk_fp8_f32)
DI uint32_t fp8pk(float a, float b) {
    return (uint32_t)__builtin_amdgcn_cvt_pk_fp8_f32(a, b, 0, false);
}
#else
DI uint32_t fp8pk(float a, float b) {
    uint32_t r;
    asm("v_cvt_pk_fp8_f32 %0, %1, %2" : "=v"(r) : "v"(a), "v"(b));
    return r;
}
#endif
#if __has_builtin(__builtin_amdgcn_cvt_f32_fp8)
#define FP8DEC(dw, sel) __builtin_amdgcn_cvt_f32_fp8((dw), (sel))
#else
DI float fp8dec_(uint32_t dw, int sel) {          // manual e4m3fn decode
    const uint32_t u = (dw >> (8 * sel)) & 0xFFu;
    const uint32_t s = (u & 0x80u) << 24;
    const uint32_t em = u & 0x7Fu;
    float mag;
    if (em >= 8) mag = __builtin_bit_cast(float, (((em >> 3) + 120u) << 23) | ((em & 7u) << 20));
    else         mag = (float)em * 0.001953125f; // m * 2^-9
    return __builtin_bit_cast(float, s | __builtin_bit_cast(uint32_t, mag));
}
#define FP8DEC(dw, sel) fp8dec_((dw), (sel))
#endif
// async global->LDS, 16B/lane (dest = wave-uniform base + lane*16)
DI void gload16(const void* g, void* s) {
    __builtin_amdgcn_global_load_lds(
        (const __attribute__((address_space(1))) uint32_t*)g,
        (__attribute__((address_space(3))) uint32_t*)s, 16, 0, 0);
}
// m204 bijective XCD-chunk swizzle
DI int xcd_swizzle(int orig, int nwg) {
    const int q = nwg >> 3, r = nwg & 7;
    const int x = orig & 7, i = orig >> 3;
    return (x < r ? x * (q + 1) : r * (q + 1) + (x - r) * q) + i;
}

// ---------- problem constants ----------
constexpr int BATCH = 8, HH_IMG = 56, WW_IMG = 56, C = 192;
constexpr int HEADS = 6, HD = 32, NA = 486;
constexpr int NAPB = 576;                              // fp8 bytes/row (6 heads * 96)
constexpr int HSTA = 96;                               // fp8 bytes/head (81 + pad)
constexpr int MROWS = BATCH * HH_IMG * WW_IMG;         // 25088
constexpr int KK = 192;
constexpr int TILE_B  = 49152;                         // B tile: 128 cols x 384B
constexpr int PANEL_B = 49152;                         // A panel: 128 rows x 192k bf16
constexpr int WTB_B   = 73728;                         // Wp frag-order

// =======================================================================
// prep_all — r10 version; weight tiles remapped to 96-per-head padding
// (768 unified cols = exactly 6 tiles of 128).
// =======================================================================
__global__ __launch_bounds__(256) void prep_all(const float* __restrict__ x,
                                                const float* __restrict__ Wv,
                                                const float* __restrict__ Wa,
                                                const float* __restrict__ Wp,
                                                const float* __restrict__ ba,
                                                uint8_t* __restrict__ xbf,
                                                uint8_t* __restrict__ WT,
                                                uint8_t* __restrict__ WTB,
                                                float* __restrict__ baP) {
    const int bid = blockIdx.x;
    if (bid < 2352) {
        const int g = bid * 256 + threadIdx.x;        // 602112 granules
        const int m = g / 24, cc = g % 24;
        const int ks = cc >> 2, lg = cc & 3;
        const float* src = x + (size_t)m * KK + cc * 8;
        const float4 v0 = *(const float4*)src;
        const float4 v1 = *(const float4*)(src + 4);
        uint4 o;
        o.x = cvtpk(v0.x, v0.y); o.y = cvtpk(v0.z, v0.w);
        o.z = cvtpk(v1.x, v1.y); o.w = cvtpk(v1.z, v1.w);
        const size_t off = (size_t)(m >> 7) * PANEL_B +
                           ((((m >> 4) & 7) * 6 + ks) * 64 + (lg << 4) + (m & 15)) * 16;
        *(uint4*)(xbf + off) = o;
        return;
    }
    const int tid = (bid - 2352) * 256 + threadIdx.x;
    if (tid < 18432) {
        const int s = tid % 24, rem = tid / 24;
        const int p = rem & 127, tile = rem >> 7;
        const int lc = (p >> 5) * 32 + 2 * (p & 15) + ((p >> 4) & 1);
        const int u  = tile * 128 + lc;               // unified col 0..767
        const float* src = nullptr; int nc = 0, col = 0;
        if (u < 192) { src = Wv; nc = 192; col = u; }
        else {
            const int up = u - 192;                   // 0..575
            const int head = up / HSTA, r96 = up - head * HSTA;
            if (r96 < 81) { src = Wa; nc = NA; col = head * 81 + r96; }
        }
        const int k0 = s * 8;
        uint32_t d[4];
#pragma unroll
        for (int e = 0; e < 4; ++e) {
            const float f0 = src ? src[(size_t)(k0 + 2 * e) * nc + col]     : 0.f;
            const float f1 = src ? src[(size_t)(k0 + 2 * e + 1) * nc + col] : 0.f;
            d[e] = cvtpk(f0, f1);
        }
        const int sb = (s * 16) ^ ((p & 7) << 4);
        *(uint4*)(WT + (size_t)tile * TILE_B + p * 384 + sb) =
            make_uint4(d[0], d[1], d[2], d[3]);
    } else if (tid < 18432 + 4608) {
        const int g = tid - 18432;
        const int l = g & 63, gg = g >> 6;
        const int ks = gg % 6, nrIdx = gg / 6;
        const int pp = nrIdx >> 1, h = nrIdx & 1;
        const int col = pp * 32 + 2 * (l & 15) + h;
        const int k0  = ks * 32 + (l >> 4) * 8;
        uint32_t d[4];
#pragma unroll
        for (int e = 0; e < 4; ++e) {
            const float f0 = Wp[(size_t)(k0 + 2 * e) * 192 + col];
            const float f1 = Wp[(size_t)(k0 + 2 * e + 1) * 192 + col];
            d[e] = cvtpk(f0, f1);
        }
        *(uint4*)(WTB + (size_t)g * 16) = make_uint4(d[0], d[1], d[2], d[3]);
    } else if (tid < 18432 + 4608 + NAPB) {
        const int pc = tid - 18432 - 4608;            // 0..575
        const int head = pc / HSTA, r96 = pc - head * HSTA;
        baP[pc] = (r96 < 81) ? ba[head * 81 + r96] : 0.f;
    }
}

// =======================================================================
// gemm_fr — r10 version; ONLY the alog epilogue changes: fp8 stores at
// byte stride 576.
// =======================================================================
__global__ __launch_bounds__(256, 2) void gemm_fr(
    const uint8_t* __restrict__ Afr,
    const uint8_t* __restrict__ WT,
    uint16_t* __restrict__ zOut, uint8_t* __restrict__ alogP,
    const float* __restrict__ baP) {
    __shared__ __align__(16) uint8_t sm[TILE_B];
    const int t    = threadIdx.x;
    const int wgid = xcd_swizzle(blockIdx.x, gridDim.x);
    const int mg   = wgid / 6, ti = wgid - mg * 6;
    const int m0   = mg * 128;
    const int l    = t & 63, wid = t >> 6;
    const int wr   = wid >> 1, wc = wid & 1;
    const int lr   = l & 15, lg = l >> 4;

    const uint8_t* wt = WT + (size_t)ti * TILE_B;
#pragma unroll
    for (int i = 0; i < 12; ++i) {
        const int off = wid * 12288 + i * 1024;
        gload16(wt + off + l * 16, sm + off);
    }

    const uint8_t* ap = Afr + (size_t)mg * PANEL_B;
    short8 aR[6][4];
#pragma unroll
    for (int ks = 0; ks < 6; ++ks)
#pragma unroll
        for (int mr = 0; mr < 4; ++mr) {
            const int r = wr * 4 + mr;
            aR[ks][mr] = *(const short8*)(ap + (size_t)(((r * 6 + ks) * 64) + l) * 16);
        }
    __syncthreads();       // drains B DMA once

    f32x4 acc[4][4];
#pragma unroll
    for (int mr = 0; mr < 4; ++mr)
#pragma unroll
        for (int nr = 0; nr < 4; ++nr) acc[mr][nr] = f32x4{0.f, 0.f, 0.f, 0.f};
#pragma unroll
    for (int ks = 0; ks < 6; ++ks) {
        const int cb = ks * 64 + lg * 16;
        short8 b[4];
#pragma unroll
        for (int nr = 0; nr < 4; ++nr) {
            const int rn = wc * 64 + nr * 16 + lr;
            b[nr] = *(const short8*)(sm + rn * 384 + (cb ^ ((rn & 7) << 4)));
        }
#pragma unroll
        for (int mr = 0; mr < 4; ++mr)
#pragma unroll
            for (int nr = 0; nr < 4; ++nr)
                acc[mr][nr] = __builtin_amdgcn_mfma_f32_16x16x32_bf16(
                    aR[ks][mr], b[nr], acc[mr][nr], 0, 0, 0);
    }

    const int gcol0 = ti * 128 + wc * 64;
#pragma unroll
    for (int pr = 0; pr < 2; ++pr) {
        const int uc = gcol0 + pr * 32 + 2 * lr;
        if (uc < 192) {
#pragma unroll
            for (int mr = 0; mr < 4; ++mr) {
                const size_t rb = (size_t)(m0 + wr * 64 + mr * 16 + lg * 4);
#pragma unroll
                for (int j = 0; j < 4; ++j)
                    *(uint32_t*)(zOut + (rb + j) * 192 + uc) =
                        cvtpk(acc[mr][2 * pr][j], acc[mr][2 * pr + 1][j]);
            }
        } else {
            const int pc = uc - 192;                  // 0..575, even
            const float be = baP[pc], bo = baP[pc + 1];
#pragma unroll
            for (int mr = 0; mr < 4; ++mr) {
                const size_t rb = (size_t)(m0 + wr * 64 + mr * 16 + lg * 4);
#pragma unroll
                for (int j = 0; j < 4; ++j)
                    *(uint16_t*)(alogP + (rb + j) * NAPB + pc) =
                        (uint16_t)fp8pk(acc[mr][2 * pr][j] + be,
                                        acc[mr][2 * pr + 1][j] + bo);
            }
        }
    }
}

// =======================================================================
// attn_fused — r10 version; phase 2 reads fp8 alog windows (template
// per-window so byte_sel is a compile-time constant).
// =======================================================================
constexpr int TH = 4, TW = 8;
constexpr int HALO_W = TW + 4;                   // 12 (halo H = 8)
constexpr int HSTR = 80;                         // z bytes/head in LDS (64+16 pad)
constexpr int PXSTR = HEADS * HSTR;              // 480 B per halo pixel
constexpr int VL_BYTES = 96 * PXSTR;             // 46080

template <int I, int J>
DI void wincoef(const uint8_t* __restrict__ rp, float (&cw)[5][5]) {
    constexpr int OFF = (I * 3 + J) * 9, A0 = OFF & ~15, BASE = OFF - A0;
    const uint4 u0 = *(const uint4*)(rp + A0);
    const uint4 u1 = *(const uint4*)(rp + A0 + 16);
    const uint32_t dd[8] = {u0.x, u0.y, u0.z, u0.w, u1.x, u1.y, u1.z, u1.w};
    constexpr float scl2 = 0.17677669529663687f * 1.4426950408889634f;  // scale*log2e
    float w[9], s = 0.f;
#define DECQ(Q) w[Q] = __builtin_amdgcn_exp2f(                                 \
        FP8DEC(dd[(BASE + Q) >> 2], (BASE + Q) & 3) * scl2); s += w[Q];
    DECQ(0) DECQ(1) DECQ(2) DECQ(3) DECQ(4) DECQ(5) DECQ(6) DECQ(7) DECQ(8)
#undef DECQ
    const float inv = __builtin_amdgcn_rcpf(s);
#pragma unroll
    for (int qi = 0; qi < 3; ++qi)
#pragma unroll
        for (int qj = 0; qj < 3; ++qj)
            cw[qi - I + 2][qj - J + 2] += w[qi * 3 + qj] * inv;
}

__global__ __launch_bounds__(192) void attn_fused(const uint16_t* __restrict__ z,
                                                  const uint8_t* __restrict__ alogP,
                                                  const uint8_t* __restrict__ WTB,
                                                  const float* __restrict__ bp,
                                                  float* __restrict__ out) {
    __shared__ __align__(16) uint8_t smem[VL_BYTES];   // vl; yl aliases [0,12288)
    const int b   = blockIdx.z;
    const int ty0 = blockIdx.y * TH, tx0 = blockIdx.x * TW;
    const int t   = threadIdx.x;

    // ---- phase 1: stage z halo (head-padded layout) ----
#pragma unroll
    for (int it = 0; it < 12; ++it) {
        const int f  = t + it * 192;             // 96 px * 24 8-ch groups
        const int px = f / 24, c8 = f % 24;
        const int hy = px / HALO_W, hx = px % HALO_W;
        const int y = ty0 + hy - 2, x = tx0 + hx - 2;
        uint4 val = make_uint4(0u, 0u, 0u, 0u);
        if ((unsigned)y < HH_IMG && (unsigned)x < WW_IMG)
            val = *(const uint4*)&z[(((size_t)b * HH_IMG + y) * WW_IMG + x) * C + c8 * 8];
        *(uint4*)(smem + px * PXSTR + (c8 >> 2) * HSTR + (c8 & 3) * 16) = val;
    }

    const int n   = t % HEADS, pxl = t / HEADS;
    const int py  = pxl >> 3, px_ = pxl & 7;
    const int Py  = ty0 + py, Px = tx0 + px_;

    // ---- phase 2: fold coefficients from fp8 alog ----
    float cw[5][5] = {};
#define WINCALL(I_, J_)                                                        \
    {                                                                          \
        const int sy = Py - I_ + 1, sx = Px - J_ + 1;                          \
        if ((unsigned)sy < HH_IMG && (unsigned)sx < WW_IMG)                    \
            wincoef<I_, J_>(alogP +                                            \
                (((size_t)b * HH_IMG + sy) * WW_IMG + sx) * NAPB + n * HSTA,   \
                cw);                                                           \
    }
    WINCALL(0, 0) WINCALL(0, 1) WINCALL(0, 2)
    WINCALL(1, 0) WINCALL(1, 1) WINCALL(1, 2)
    WINCALL(2, 0) WINCALL(2, 1) WINCALL(2, 2)
#undef WINCALL
    __syncthreads();   // staging complete before gather

    // ---- phase 3: 25-offset gather (conflict-free banks) ----
    float acc[HD] = {};
#pragma unroll
    for (int dy = 0; dy < 5; ++dy)
#pragma unroll
        for (int dx = 0; dx < 5; ++dx) {
            const float wq = cw[dy][dx];
            const uint8_t* vp = smem + ((py + dy) * HALO_W + (px_ + dx)) * PXSTR + n * HSTR;
#pragma unroll
            for (int v8 = 0; v8 < 4; ++v8) {
                const uint4 raw = *(const uint4*)(vp + v8 * 16);
                const uint32_t r0 = raw.x, r1 = raw.y, r2 = raw.z, r3 = raw.w;
                acc[v8*8+0] = fmaf(wq, bflo(r0), acc[v8*8+0]);
                acc[v8*8+1] = fmaf(wq, bfhi(r0), acc[v8*8+1]);
                acc[v8*8+2] = fmaf(wq, bflo(r1), acc[v8*8+2]);
                acc[v8*8+3] = fmaf(wq, bfhi(r1), acc[v8*8+3]);
                acc[v8*8+4] = fmaf(wq, bflo(r2), acc[v8*8+4]);
                acc[v8*8+5] = fmaf(wq, bfhi(r2), acc[v8*8+5]);
                acc[v8*8+6] = fmaf(wq, bflo(r3), acc[v8*8+6]);
                acc[v8*8+7] = fmaf(wq, bfhi(r3), acc[v8*8+7]);
            }
        }
    __syncthreads();   // all gathers done -> vl region may be reused as yl

    // ---- ypre -> LDS (aliases vl; bf16, XOR-swizzled 384B rows) ----
    {
        uint8_t* pb = smem + pxl * 384;
        const int key = (pxl & 7) << 4;
#pragma unroll
        for (int g2 = 0; g2 < 4; ++g2) {
            uint4 o;
            o.x = cvtpk(acc[g2 * 8 + 0], acc[g2 * 8 + 1]);
            o.y = cvtpk(acc[g2 * 8 + 2], acc[g2 * 8 + 3]);
            o.z = cvtpk(acc[g2 * 8 + 4], acc[g2 * 8 + 5]);
            o.w = cvtpk(acc[g2 * 8 + 6], acc[g2 * 8 + 7]);
            *(uint4*)(pb + ((n * 64 + g2 * 16) ^ key)) = o;
        }
    }
    __syncthreads();

    // ---- phase 4: out = ypre @ Wp + bp ----
    const int l = t & 63, wid = t >> 6;
    const int lr = l & 15, lg = l >> 4;
    short8 aF[2][6];
#pragma unroll
    for (int r = 0; r < 2; ++r)
#pragma unroll
        for (int ks = 0; ks < 6; ++ks) {
            const int row = r * 16 + lr;
            aF[r][ks] = *(const short8*)(smem + row * 384 +
                          ((ks * 64 + lg * 16) ^ ((row & 7) << 4)));
        }
    f32x4 gacc[2][4];
#pragma unroll
    for (int r = 0; r < 2; ++r)
#pragma unroll
        for (int f = 0; f < 4; ++f) gacc[r][f] = f32x4{0.f, 0.f, 0.f, 0.f};
#pragma unroll
    for (int ks = 0; ks < 6; ++ks) {
        short8 bF[4];
#pragma unroll
        for (int f = 0; f < 4; ++f) {
            const int nrIdx = wid * 4 + f;
            bF[f] = *(const short8*)(WTB + (size_t)(((nrIdx * 6 + ks) * 64) + l) * 16);
        }
#pragma unroll
        for (int r = 0; r < 2; ++r)
#pragma unroll
            for (int f = 0; f < 4; ++f)
                gacc[r][f] = __builtin_amdgcn_mfma_f32_16x16x32_bf16(
                    aF[r][ks], bF[f], gacc[r][f], 0, 0, 0);
    }

#pragma unroll
    for (int pi = 0; pi < 2; ++pi) {
        const int col = wid * 64 + pi * 32 + 2 * lr;
        const float be = bp[col], bo = bp[col + 1];
#pragma unroll
        for (int r = 0; r < 2; ++r)
#pragma unroll
            for (int j = 0; j < 4; ++j) {
                const int prow = r * 16 + lg * 4 + j;
                const int gy = ty0 + (prow >> 3), gx = tx0 + (prow & 7);
                float* op = out + (((size_t)b * HH_IMG + gy) * WW_IMG + gx) * C + col;
                *(float2*)op = make_float2(gacc[r][2 * pi][j] + be,
                                           gacc[r][2 * pi + 1][j] + bo);
            }
    }
}

// =======================================================================
extern "C" void kernel_launch(void* const* d_in, const int* in_sizes, int n_in,
                              void* d_out, int out_size, void* d_ws, size_t ws_size,
                              hipStream_t stream) {
    const float* x  = (const float*)d_in[0];
    const float* Wv = (const float*)d_in[1];
    const float* Wa = (const float*)d_in[2];
    const float* ba = (const float*)d_in[3];
    const float* Wp = (const float*)d_in[4];
    const float* bp = (const float*)d_in[5];
    float* out = (float*)d_out;

    // ws: z | alogP(fp8) | xbf | WT | WTB | baP
    uint16_t* z     = (uint16_t*)d_ws;
    uint8_t*  alogP = (uint8_t*)(z + (size_t)MROWS * C);
    uint8_t*  xbf   = alogP + (size_t)MROWS * NAPB;
    uint8_t*  WT    = xbf + (size_t)(MROWS / 128) * PANEL_B;
    uint8_t*  WTB   = WT + 6 * (size_t)TILE_B;
    float*    baP   = (float*)(WTB + WTB_B);

    // prep: x->frag-order (2352 blocks) + tiles/WTB/baP (93 blocks)
    prep_all<<<2352 + 93, 256, 0, stream>>>(x, Wv, Wa, Wp, ba, xbf, WT, WTB, baP);
    // projections: 6 unified tiles -> z (uc<192) + alogP (fp8, +baP)
    gemm_fr<<<(MROWS / 128) * 6, 256, 0, stream>>>(xbf, WT, z, alogP, baP);
    // softmax + fold + final GEMM -> out
    attn_fused<<<dim3(WW_IMG / TW, HH_IMG / TH, BATCH), dim3(192), 0, stream>>>(
        z, alogP, WTB, bp, out);
}